// Round 2
// baseline (1112.898 us; speedup 1.0000x reference)
//
#include <hip/hip_runtime.h>
#include <math.h>

// CrossAttentionLayer_two_level fused kernel for MI355X (gfx950).
// All inputs/outputs fp32 (per reference); bf16 MFMA with fp32 accumulation.
// One workgroup per batch. prep_kernel folds LN+Wq+Wk into QW (64x128 bf16)
// and qb (64 f32) stored in d_ws.

typedef __bf16 v8bf __attribute__((ext_vector_type(8)));
typedef float  v4f  __attribute__((ext_vector_type(4)));

static __device__ __forceinline__ v4f mfma16(v8bf a, v8bf b, v4f c) {
  return __builtin_amdgcn_mfma_f32_16x16x32_bf16(a, b, c, 0, 0, 0);
}

// load 8 consecutive floats, round to bf16 fragment
static __device__ __forceinline__ v8bf cvt8(const float* __restrict__ p) {
  float4 a = *(const float4*)p;
  float4 b = *(const float4*)(p + 4);
  v8bf f;
  f[0] = (__bf16)a.x; f[1] = (__bf16)a.y; f[2] = (__bf16)a.z; f[3] = (__bf16)a.w;
  f[4] = (__bf16)b.x; f[5] = (__bf16)b.y; f[6] = (__bf16)b.z; f[7] = (__bf16)b.w;
  return f;
}

// ---------------- prep: q = LN(query)@Wq.T + bq;  QW[c=h*8+i] = 0.25*Wk_h^T q_h[i]
__global__ __launch_bounds__(256)
void prep_kernel(const float* __restrict__ query,
                 const float* __restrict__ g1, const float* __restrict__ b1,
                 const float* __restrict__ Wq, const float* __restrict__ bq,
                 const float* __restrict__ Wk, const float* __restrict__ bk,
                 __bf16* __restrict__ qw, float* __restrict__ qb)
{
  __shared__ float qn[8*128];
  __shared__ float qp[8*128];
  const int t = threadIdx.x;
  for (int idx = t; idx < 1024; idx += 256) qn[idx] = query[idx];
  __syncthreads();
  {
    const int w = t >> 6, L = t & 63;
    const int row = 2*w + (L >> 5), col = L & 31;
    float x[4], s = 0.f, sq = 0.f;
    for (int p = 0; p < 4; p++) { x[p] = qn[row*128 + col + 32*p]; s += x[p]; sq += x[p]*x[p]; }
    for (int m = 1; m < 32; m <<= 1) { s += __shfl_xor(s, m); sq += __shfl_xor(sq, m); }
    const float mean = s * (1.f/128.f);
    const float var  = sq * (1.f/128.f) - mean*mean;
    const float rs   = rsqrtf(var + 1e-5f);
    for (int p = 0; p < 4; p++) {
      const int e = col + 32*p;
      qn[row*128 + e] = (x[p]-mean)*rs*g1[e] + b1[e];
    }
  }
  __syncthreads();
  {
    const int i = t >> 5, o0 = t & 31;
    for (int p = 0; p < 4; p++) {
      const int o = o0 + 32*p;
      float acc = bq[o];
      for (int e = 0; e < 128; e++) acc += qn[i*128 + e] * Wq[o*128 + e];
      qp[i*128 + o] = acc;
    }
  }
  __syncthreads();
  {
    const int cc = t >> 2, e0 = (t & 3) * 32;
    const int h = cc >> 3, i = cc & 7;
    float qv[16];
    for (int d = 0; d < 16; d++) qv[d] = qp[i*128 + 16*h + d];
    for (int e = e0; e < e0 + 32; e++) {
      float acc = 0.f;
      for (int d = 0; d < 16; d++) acc += qv[d] * Wk[(16*h + d)*128 + e];
      qw[cc*136 + e] = (__bf16)(0.25f * acc);
    }
    if (t < 64) {
      const int h2 = t >> 3, i2 = t & 7;
      float acc = 0.f;
      for (int d = 0; d < 16; d++) acc += qp[i2*128 + 16*h2 + d] * bk[16*h2 + d];
      qb[t] = 0.25f * acc;
    }
  }
}

// ---------------- main fused kernel: one block per batch
__global__ __launch_bounds__(256, 3)
void fused_kernel(const float* __restrict__ query,
                  const float* __restrict__ tgt,
                  const float* __restrict__ Wv, const float* __restrict__ bv,
                  const float* __restrict__ Wp, const float* __restrict__ bp,
                  const float* __restrict__ g2, const float* __restrict__ b2,
                  const float* __restrict__ Wf1, const float* __restrict__ bf1,
                  const float* __restrict__ Wf2, const float* __restrict__ bf2,
                  const __bf16* __restrict__ qw, const float* __restrict__ qb,
                  float* __restrict__ out)
{
  // LDS layouts: rows padded for 16B alignment + even bank spread.
  __shared__ __align__(16) __bf16 s_tgt[48*136];   // [j][e]  A-operand
  __shared__ __align__(16) __bf16 s_P[64*72];      // [c][j]  A-operand for PV; reused as fp32 store stage
  __shared__ __align__(16) __bf16 s_vT[128*72];    // [col][j] B-operand
  __shared__ __align__(16) __bf16 s_act[16*136];   // [row][col] A-operand for Wp/Wf1/Wf2
  __shared__ float s_stats[4][16][2];

  const int b  = blockIdx.x;
  const int t  = threadIdx.x;
  const int w  = t >> 6;       // wave 0..3
  const int L  = t & 63;
  const int ln = L & 15;       // MFMA m/n lane
  const int g  = L >> 4;       // quad

  // ---- P0: stage tgt tile (fp32 -> bf16), zero vT j-pad [48,64)
  {
    const float* tg = tgt + (long)b * 6144;
    for (int c8 = t; c8 < 768; c8 += 256) {
      v8bf v = cvt8(&tg[c8*8]);
      const int j = c8 >> 4, k8 = (c8 & 15) * 8;
      *(v8bf*)&s_tgt[j*136 + k8] = v;
    }
    for (int idx = t; idx < 2048; idx += 256)
      s_vT[(idx >> 4)*72 + 48 + (idx & 15)] = (__bf16)0.f;
  }
  __syncthreads();

  const int c = w*16 + ln;     // dots column (h*8+i); wave w owns n-tile w

  // ---- P1: dots = tgt@QW.T  and  v = tgt@Wv.T
  v4f dacc[3], vacc[3][2];
  {
    v8bf qwf[4], wvf[2][4];
    for (int ks = 0; ks < 4; ks++)
      qwf[ks] = *(const v8bf*)&qw[c*136 + ks*32 + g*8];
    for (int nt = 0; nt < 2; nt++)
      for (int ks = 0; ks < 4; ks++)
        wvf[nt][ks] = cvt8(&Wv[(w*32 + nt*16 + ln)*128 + ks*32 + g*8]);
    const v4f z = {0.f, 0.f, 0.f, 0.f};
    for (int mt = 0; mt < 3; mt++) { dacc[mt] = z; vacc[mt][0] = z; vacc[mt][1] = z; }
    for (int mt = 0; mt < 3; mt++) {
      v8bf af[4];
      for (int ks = 0; ks < 4; ks++)
        af[ks] = *(const v8bf*)&s_tgt[(mt*16 + ln)*136 + ks*32 + g*8];
      for (int ks = 0; ks < 4; ks++) {
        dacc[mt]    = mfma16(af[ks], qwf[ks],    dacc[mt]);
        vacc[mt][0] = mfma16(af[ks], wvf[0][ks], vacc[mt][0]);
        vacc[mt][1] = mfma16(af[ks], wvf[1][ks], vacc[mt][1]);
      }
    }
  }
  // softmax over j (48) per column c, window-masked; write P and vT
  {
    const int i = c & 7;
    const float qbv = qb[c];
    const bool allv = (i < 2);
    int hsp = 0, wsp = 0;
    if (!allv) { const int idx = i - 2; hsp = idx / 3; wsp = idx - 3*hsp; }
    float dv[12];
    float mx = -1e30f;
    for (int mt = 0; mt < 3; mt++)
      for (int r = 0; r < 4; r++) {
        const int j  = mt*16 + g*4 + r;
        const int rr = j / 6, ccol = j - rr*6;
        const bool valid = allv || (((rr >> 2) == hsp) && ((ccol >> 1) == wsp));
        const float dd = valid ? dacc[mt][r] + qbv : -1e30f;
        dv[mt*4 + r] = dd;
        mx = fmaxf(mx, dd);
      }
    mx = fmaxf(mx, __shfl_xor(mx, 16));
    mx = fmaxf(mx, __shfl_xor(mx, 32));
    float sm = 0.f;
    for (int p = 0; p < 12; p++) {
      const float e = (dv[p] > -1e29f) ? __expf(dv[p] - mx) : 0.f;
      dv[p] = e; sm += e;
    }
    sm += __shfl_xor(sm, 16);
    sm += __shfl_xor(sm, 32);
    const float inv = 1.f / sm;
    for (int mt = 0; mt < 3; mt++)
      for (int r = 0; r < 4; r++)
        s_P[c*72 + mt*16 + g*4 + r] = (__bf16)(dv[mt*4 + r] * inv);
    for (int idx = t; idx < 1024; idx += 256)   // zero P j-pad [48,64)
      s_P[(idx >> 4)*72 + 48 + (idx & 15)] = (__bf16)0.f;
    for (int nt = 0; nt < 2; nt++) {
      const int o = w*32 + nt*16 + ln;
      const float bvo = bv[o];
      for (int mt = 0; mt < 3; mt++)
        for (int r = 0; r < 4; r++)
          s_vT[o*72 + mt*16 + g*4 + r] = (__bf16)(vacc[mt][nt][r] + bvo);
    }
  }
  __syncthreads();

  // ---- P3: PV. m-tile w holds heads 2w,2w+1; valid n-quadrant selected at write.
  {
    const v4f z = {0.f,0.f,0.f,0.f};
    v4f oacc[2] = {z, z};
    for (int ks = 0; ks < 2; ks++) {
      v8bf pf = *(const v8bf*)&s_P[(w*16 + ln)*72 + ks*32 + g*8];
      for (int nt = 0; nt < 2; nt++) {
        v8bf vf = *(const v8bf*)&s_vT[(w*32 + nt*16 + ln)*72 + ks*32 + g*8];
        oacc[nt] = mfma16(pf, vf, oacc[nt]);
      }
    }
    const int ntv = g >> 1;                 // valid quadrant: head matches col chunk
    const int o = w*32 + ntv*16 + ln;
    for (int r = 0; r < 4; r++) {
      const int i = (g*4 + r) & 7;
      s_act[i*136 + o] = (__bf16)oacc[ntv][r];
    }
    for (int idx = t; idx < 1088; idx += 256)  // zero act rows 8..15
      s_act[8*136 + idx] = (__bf16)0.f;
  }
  __syncthreads();

  // ---- P4: x = query + act@Wp.T + bp ; LN partial stats
  float xs[2][4];
  {
    v8bf wpf[2][4];
    for (int nt = 0; nt < 2; nt++)
      for (int ks = 0; ks < 4; ks++)
        wpf[nt][ks] = cvt8(&Wp[(w*32 + nt*16 + ln)*128 + ks*32 + g*8]);
    const v4f z = {0.f,0.f,0.f,0.f};
    v4f xacc[2] = {z, z};
    for (int ks = 0; ks < 4; ks++) {
      v8bf af = *(const v8bf*)&s_act[ln*136 + ks*32 + g*8];
      xacc[0] = mfma16(af, wpf[0][ks], xacc[0]);
      xacc[1] = mfma16(af, wpf[1][ks], xacc[1]);
    }
    for (int nt = 0; nt < 2; nt++) {
      const int o = w*32 + nt*16 + ln;
      for (int r = 0; r < 4; r++) {
        const int R = g*4 + r;
        float v = xacc[nt][r];
        if (R < 8) v += query[R*128 + o] + bp[o];
        else       v = 0.f;                 // keep pad rows exactly zero
        xs[nt][r] = v;
      }
    }
    for (int r = 0; r < 4; r++) {
      float a  = xs[0][r] + xs[1][r];
      float q2 = xs[0][r]*xs[0][r] + xs[1][r]*xs[1][r];
      for (int m = 1; m < 16; m <<= 1) { a += __shfl_xor(a, m); q2 += __shfl_xor(q2, m); }
      if (ln == 0) { s_stats[w][g*4 + r][0] = a; s_stats[w][g*4 + r][1] = q2; }
    }
  }
  __syncthreads();

  // ---- P5: LN normalize -> xn into act
  for (int r = 0; r < 4; r++) {
    const int R = g*4 + r;
    const float s  = s_stats[0][R][0] + s_stats[1][R][0] + s_stats[2][R][0] + s_stats[3][R][0];
    const float sq = s_stats[0][R][1] + s_stats[1][R][1] + s_stats[2][R][1] + s_stats[3][R][1];
    const float mean = s * (1.f/128.f);
    const float var  = sq * (1.f/128.f) - mean*mean;
    const float rs   = rsqrtf(var + 1e-5f);
    for (int nt = 0; nt < 2; nt++) {
      const int o = w*32 + nt*16 + ln;
      const float v = (xs[nt][r] - mean)*rs*g2[o] + b2[o];
      s_act[R*136 + o] = (__bf16)v;
    }
  }
  __syncthreads();

  // ---- P6: h = gelu(xn@Wf1.T + bf1)  (exact gelu)
  float hv[2][4];
  {
    v8bf wf[2][4];
    for (int nt = 0; nt < 2; nt++)
      for (int ks = 0; ks < 4; ks++)
        wf[nt][ks] = cvt8(&Wf1[(w*32 + nt*16 + ln)*128 + ks*32 + g*8]);
    const v4f z = {0.f,0.f,0.f,0.f};
    v4f hacc[2] = {z, z};
    for (int ks = 0; ks < 4; ks++) {
      v8bf af = *(const v8bf*)&s_act[ln*136 + ks*32 + g*8];
      hacc[0] = mfma16(af, wf[0][ks], hacc[0]);
      hacc[1] = mfma16(af, wf[1][ks], hacc[1]);
    }
    for (int nt = 0; nt < 2; nt++) {
      const int o = w*32 + nt*16 + ln;
      const float b1v = bf1[o];
      for (int r = 0; r < 4; r++) {
        const float x = hacc[nt][r] + b1v;
        hv[nt][r] = 0.5f*x*(1.f + erff(x*0.70710678118654752f));
      }
    }
  }
  __syncthreads();   // all act reads done before overwrite
  for (int nt = 0; nt < 2; nt++) {
    const int o = w*32 + nt*16 + ln;
    for (int r = 0; r < 4; r++)
      s_act[(g*4 + r)*136 + o] = (__bf16)hv[nt][r];
  }
  __syncthreads();

  // ---- P7: y = h@Wf2.T + bf2 ; final = x + y ; coalesced fp32 store
  {
    v8bf wf[2][4];
    for (int nt = 0; nt < 2; nt++)
      for (int ks = 0; ks < 4; ks++)
        wf[nt][ks] = cvt8(&Wf2[(w*32 + nt*16 + ln)*128 + ks*32 + g*8]);
    const v4f z = {0.f,0.f,0.f,0.f};
    v4f yacc[2] = {z, z};
    for (int ks = 0; ks < 4; ks++) {
      v8bf af = *(const v8bf*)&s_act[ln*136 + ks*32 + g*8];
      yacc[0] = mfma16(af, wf[0][ks], yacc[0]);
      yacc[1] = mfma16(af, wf[1][ks], yacc[1]);
    }
    float* stagef = (float*)s_P;               // s_P dead since P3; 9216B >= 4096B
    for (int nt = 0; nt < 2; nt++) {
      const int o = w*32 + nt*16 + ln;
      const float b2v = bf2[o];
      for (int r = 0; r < 4; r++) {
        const int R = g*4 + r;
        if (R < 8)
          stagef[R*128 + o] = xs[nt][r] + yacc[nt][r] + b2v;
      }
    }
  }
  __syncthreads();
  {
    const float* stagef = (const float*)s_P;
    float4 v = *(const float4*)&stagef[t*4];
    *(float4*)&out[(long)b*1024 + t*4] = v;
  }
}

extern "C" void kernel_launch(void* const* d_in, const int* in_sizes, int n_in,
                              void* d_out, int out_size, void* d_ws, size_t ws_size,
                              hipStream_t stream)
{
  const float* query = (const float*)d_in[0];
  const float* tgt   = (const float*)d_in[1];
  const float* g1    = (const float*)d_in[2];
  const float* b1    = (const float*)d_in[3];
  const float* Wq    = (const float*)d_in[4];
  const float* bq    = (const float*)d_in[5];
  const float* Wk    = (const float*)d_in[6];
  const float* bk    = (const float*)d_in[7];
  const float* Wv    = (const float*)d_in[8];
  const float* bv    = (const float*)d_in[9];
  const float* Wp    = (const float*)d_in[10];
  const float* bp    = (const float*)d_in[11];
  const float* g2    = (const float*)d_in[12];
  const float* b2    = (const float*)d_in[13];
  const float* Wf1   = (const float*)d_in[14];
  const float* bf1   = (const float*)d_in[15];
  const float* Wf2   = (const float*)d_in[16];
  const float* bf2   = (const float*)d_in[17];
  float* out = (float*)d_out;

  __bf16* qw = (__bf16*)d_ws;                      // 64 x 136 bf16 = 17408 B
  float*  qb = (float*)((char*)d_ws + 64*136*2);   // 64 f32

  const int nB = in_sizes[1] / (48 * 128);         // 16384

  prep_kernel<<<1, 256, 0, stream>>>(query, g1, b1, Wq, bq, Wk, bk, qw, qb);
  fused_kernel<<<nB, 256, 0, stream>>>(query, tgt, Wv, bv, Wp, bp, g2, b2,
                                       Wf1, bf1, Wf2, bf2, qw, qb, out);
}